// Round 6
// baseline (132.666 us; speedup 1.0000x reference)
//
#include <hip/hip_runtime.h>
#include <cstddef>
#include <cstdint>

#define POS_LEN    32768
#define NUM_NEG    64
#define N_RULES    262144
#define N_UNLABEL  131072
#define NUM_ENT    100000
#define NUM_REL    500
#define EMB_DIM    256
#define WEIGHT_DECAY 1e-5

#define AUX_BLOCKS    2048
#define GATHER_BLOCKS 2048
#define LOSS_BLOCKS   1024

typedef __attribute__((ext_vector_type(4))) float        f32x4;
typedef __attribute__((ext_vector_type(2))) unsigned int u32x2;
typedef __attribute__((ext_vector_type(8))) _Float16     h8;

__device__ __forceinline__ float softplusf_(float x) {
    return fmaxf(x, 0.0f) + log1pf(expf(-fabsf(x)));
}
__device__ __forceinline__ float sigmoidf_(float x) {
    return 1.0f / (1.0f + expf(-x));
}
__device__ __forceinline__ float quarter_sum16(float v) {   // reduce within 16-lane group
#pragma unroll
    for (int m = 1; m <= 8; m <<= 1) v += __shfl_xor(v, m, 64);
    return v;
}
__device__ __forceinline__ float half_sum32(float v) {
#pragma unroll
    for (int m = 1; m <= 16; m <<= 1) v += __shfl_xor(v, m, 64);
    return v;
}
__device__ __forceinline__ float wave_sum64(float v) {
#pragma unroll
    for (int m = 32; m >= 1; m >>= 1) v += __shfl_xor(v, m, 64);
    return v;
}
__device__ __forceinline__ double wave_sum64d(double v) {
#pragma unroll
    for (int m = 32; m >= 1; m >>= 1) v += __shfl_xor(v, m, 64);
    return v;
}

// pack 8 f32 -> h8 via HW cvt_pkrtz (round-toward-zero pack), explicit casts
__device__ __forceinline__ h8 f32x8_to_h8(const f32x4 a, const f32x4 b) {
    auto p0 = __builtin_amdgcn_cvt_pkrtz(a[0], a[1]);
    auto p1 = __builtin_amdgcn_cvt_pkrtz(a[2], a[3]);
    auto p2 = __builtin_amdgcn_cvt_pkrtz(b[0], b[1]);
    auto p3 = __builtin_amdgcn_cvt_pkrtz(b[2], b[3]);
    h8 o;
    o[0] = (_Float16)p0[0]; o[1] = (_Float16)p0[1];
    o[2] = (_Float16)p1[0]; o[3] = (_Float16)p1[1];
    o[4] = (_Float16)p2[0]; o[5] = (_Float16)p2[1];
    o[6] = (_Float16)p3[0]; o[7] = (_Float16)p3[1];
    return o;
}

// ---- f16 quarter-wave triple score: 16 lanes x 16 elems = 256 dims. l = lane & 15.
// Row = 32 h8 chunks; lane l covers chunks 2l, 2l+1.
#define FD2(acc, m, t, i0, i1)                                               \
    acc = __builtin_amdgcn_fdot2(                                            \
        __builtin_shufflevector(m, m, i0, i1),                               \
        __builtin_shufflevector(t, t, i0, i1), acc, false)

__device__ __forceinline__ float triple_score_f16(const h8* __restrict__ ent16,
                                                  const h8* __restrict__ rel16,
                                                  int h, int r, int t, int l) {
    const h8* hp = ent16 + (size_t)h * 32 + l * 2;
    const h8* rp = rel16 + (size_t)r * 32 + l * 2;
    const h8* tp = ent16 + (size_t)t * 32 + l * 2;
    h8 h0 = hp[0], h1 = hp[1];
    h8 r0 = rp[0], r1 = rp[1];
    h8 t0 = tp[0], t1 = tp[1];
    h8 m0 = h0 * r0;
    h8 m1 = h1 * r1;
    float acc = 0.0f;
    FD2(acc, m0, t0, 0, 1); FD2(acc, m0, t0, 2, 3);
    FD2(acc, m0, t0, 4, 5); FD2(acc, m0, t0, 6, 7);
    FD2(acc, m1, t1, 0, 1); FD2(acc, m1, t1, 2, 3);
    FD2(acc, m1, t1, 4, 5); FD2(acc, m1, t1, 6, 7);
    return quarter_sum16(acc);
}

// ---- fp8 fallback (half-wave, proven in R4) ----
__device__ __forceinline__ u32x2 f32x8_to_fp8(const f32x4 a, const f32x4 b) {
    int lo = 0, hi = 0;
    lo = __builtin_amdgcn_cvt_pk_fp8_f32(a[0], a[1], lo, false);
    lo = __builtin_amdgcn_cvt_pk_fp8_f32(a[2], a[3], lo, true);
    hi = __builtin_amdgcn_cvt_pk_fp8_f32(b[0], b[1], hi, false);
    hi = __builtin_amdgcn_cvt_pk_fp8_f32(b[2], b[3], hi, true);
    u32x2 r; r[0] = (unsigned)lo; r[1] = (unsigned)hi; return r;
}
__device__ __forceinline__ void fp8x4_to_f32(unsigned int w, float* o) {
    auto x = __builtin_amdgcn_cvt_pk_f32_fp8((int)w, false);
    auto y = __builtin_amdgcn_cvt_pk_f32_fp8((int)w, true);
    o[0] = x[0]; o[1] = x[1]; o[2] = y[0]; o[3] = y[1];
}
__device__ __forceinline__ float triple_score_fp8(const u32x2* __restrict__ ent8,
                                                  const u32x2* __restrict__ rel8,
                                                  int h, int r, int t, int l) {
    const u32x2 hv = ent8[(size_t)h * 32 + l];
    const u32x2 rv = rel8[(size_t)r * 32 + l];
    const u32x2 tv = ent8[(size_t)t * 32 + l];
    float hf[8], rf[8], tf[8];
    fp8x4_to_f32(hv[0], hf); fp8x4_to_f32(hv[1], hf + 4);
    fp8x4_to_f32(rv[0], rf); fp8x4_to_f32(rv[1], rf + 4);
    fp8x4_to_f32(tv[0], tf); fp8x4_to_f32(tv[1], tf + 4);
    float s = 0.0f;
#pragma unroll
    for (int j = 0; j < 8; ++j) s = fmaf(hf[j] * rf[j], tf[j], s);
    return half_sum32(s);
}

// ---- Kernel 1 (f16): quantize ent/rel -> f16, sum-of-squares (f32 exact),
//      zero pi_grad. Streaming reads non-temporal. Per-block partials. ----
__global__ void aux_f16_kernel(const float* __restrict__ ent,
                               const float* __restrict__ rel,
                               h8* __restrict__ ent16,
                               h8* __restrict__ rel16,
                               float* __restrict__ pi_grad,
                               float* __restrict__ auxp) {
    const int tid = blockIdx.x * blockDim.x + threadIdx.x;
    const int stride = gridDim.x * blockDim.x;
    for (int i = tid; i < N_UNLABEL; i += stride) pi_grad[i] = 0.0f;

    float sq = 0.0f;
    const f32x4* entv = reinterpret_cast<const f32x4*>(ent);
    for (int i = tid; i < (NUM_ENT * EMB_DIM) / 8; i += stride) {
        f32x4 a = __builtin_nontemporal_load(entv + (size_t)i * 2);
        f32x4 b = __builtin_nontemporal_load(entv + (size_t)i * 2 + 1);
        sq += a[0]*a[0] + a[1]*a[1] + a[2]*a[2] + a[3]*a[3]
            + b[0]*b[0] + b[1]*b[1] + b[2]*b[2] + b[3]*b[3];
        ent16[i] = f32x8_to_h8(a, b);
    }
    const f32x4* relv = reinterpret_cast<const f32x4*>(rel);
    for (int i = tid; i < (NUM_REL * EMB_DIM) / 8; i += stride) {
        f32x4 a = __builtin_nontemporal_load(relv + (size_t)i * 2);
        f32x4 b = __builtin_nontemporal_load(relv + (size_t)i * 2 + 1);
        sq += a[0]*a[0] + a[1]*a[1] + a[2]*a[2] + a[3]*a[3]
            + b[0]*b[0] + b[1]*b[1] + b[2]*b[2] + b[3]*b[3];
        rel16[i] = f32x8_to_h8(a, b);
    }
    sq = wave_sum64(sq);
    __shared__ float ls[8];
    const int lane = threadIdx.x & 63, wid = threadIdx.x >> 6;
    if (lane == 0) ls[wid] = sq;
    __syncthreads();
    if (threadIdx.x == 0) {
        float bs = 0.0f;
        for (int w = 0; w < (int)(blockDim.x >> 6); ++w) bs += ls[w];
        auxp[blockIdx.x] = bs;
    }
}

// fp8 fallback aux
__global__ void aux_fp8_kernel(const float* __restrict__ ent,
                               const float* __restrict__ rel,
                               u32x2* __restrict__ ent8,
                               u32x2* __restrict__ rel8,
                               float* __restrict__ pi_grad,
                               float* __restrict__ auxp) {
    const int tid = blockIdx.x * blockDim.x + threadIdx.x;
    const int stride = gridDim.x * blockDim.x;
    for (int i = tid; i < N_UNLABEL; i += stride) pi_grad[i] = 0.0f;
    float sq = 0.0f;
    const f32x4* entv = reinterpret_cast<const f32x4*>(ent);
    for (int i = tid; i < (NUM_ENT * EMB_DIM) / 8; i += stride) {
        f32x4 a = __builtin_nontemporal_load(entv + (size_t)i * 2);
        f32x4 b = __builtin_nontemporal_load(entv + (size_t)i * 2 + 1);
        sq += a[0]*a[0] + a[1]*a[1] + a[2]*a[2] + a[3]*a[3]
            + b[0]*b[0] + b[1]*b[1] + b[2]*b[2] + b[3]*b[3];
        ent8[i] = f32x8_to_fp8(a, b);
    }
    const f32x4* relv = reinterpret_cast<const f32x4*>(rel);
    for (int i = tid; i < (NUM_REL * EMB_DIM) / 8; i += stride) {
        f32x4 a = __builtin_nontemporal_load(relv + (size_t)i * 2);
        f32x4 b = __builtin_nontemporal_load(relv + (size_t)i * 2 + 1);
        sq += a[0]*a[0] + a[1]*a[1] + a[2]*a[2] + a[3]*a[3]
            + b[0]*b[0] + b[1]*b[1] + b[2]*b[2] + b[3]*b[3];
        rel8[i] = f32x8_to_fp8(a, b);
    }
    sq = wave_sum64(sq);
    __shared__ float ls[8];
    const int lane = threadIdx.x & 63, wid = threadIdx.x >> 6;
    if (lane == 0) ls[wid] = sq;
    __syncthreads();
    if (threadIdx.x == 0) {
        float bs = 0.0f;
        for (int w = 0; w < (int)(blockDim.x >> 6); ++w) bs += ls[w];
        auxp[blockIdx.x] = bs;
    }
}

// ---- Kernel 2 (f16): fused gathers, quarter-wave (4 triples/wave). ----
__global__ void gather_f16_kernel(const float* __restrict__ conf,
                                  const h8* __restrict__ ent16,
                                  const h8* __restrict__ rel16,
                                  const int* __restrict__ p1,
                                  const int* __restrict__ p2,
                                  const int* __restrict__ tnum,
                                  const int* __restrict__ uids,
                                  const int* __restrict__ ut,
                                  float* __restrict__ pi_grad,
                                  float* __restrict__ su_out) {
    const int lane = threadIdx.x & 63;
    const int l    = lane & 15;
    const int q    = lane >> 4;   // quarter 0..3
    const int wave  = blockIdx.x * (blockDim.x >> 6) + (threadIdx.x >> 6);
    const int nwave = gridDim.x * (blockDim.x >> 6);
    const int nr4 = N_RULES / 4, nu4 = N_UNLABEL / 4, ntot = nr4 + nu4;

    for (int pi = wave; pi < ntot; pi += nwave) {
        if (pi < nr4) {
            const int rule = pi * 4 + q;
            const int h1 = p1[rule * 3 + 0], r1 = p1[rule * 3 + 1], t1 = p1[rule * 3 + 2];
            float c = sigmoidf_(triple_score_f16(ent16, rel16, h1, r1, t1, l)) * conf[rule];
            if (tnum[rule] == 3) {   // exec-masked per quarter
                const int h2 = p2[rule * 3 + 0], r2 = p2[rule * 3 + 1], t2 = p2[rule * 3 + 2];
                c *= sigmoidf_(triple_score_f16(ent16, rel16, h2, r2, t2, l));
            }
            if (l == 0) atomicAdd(&pi_grad[uids[rule]], c);
        } else {
            const int i = (pi - nr4) * 4 + q;
            const int h = ut[i * 3 + 0], r = ut[i * 3 + 1], t = ut[i * 3 + 2];
            const float su = triple_score_f16(ent16, rel16, h, r, t, l);
            if (l == 0) su_out[i] = su;
        }
    }
}

// fp8 fallback gather (half-wave)
__global__ void gather_fp8_kernel(const float* __restrict__ conf,
                                  const u32x2* __restrict__ ent8,
                                  const u32x2* __restrict__ rel8,
                                  const int* __restrict__ p1,
                                  const int* __restrict__ p2,
                                  const int* __restrict__ tnum,
                                  const int* __restrict__ uids,
                                  const int* __restrict__ ut,
                                  float* __restrict__ pi_grad,
                                  float* __restrict__ su_out) {
    const int lane = threadIdx.x & 63;
    const int l    = lane & 31;
    const int half = lane >> 5;
    const int wave  = blockIdx.x * (blockDim.x >> 6) + (threadIdx.x >> 6);
    const int nwave = gridDim.x * (blockDim.x >> 6);
    const int nrp = N_RULES / 2, nup = N_UNLABEL / 2, ntot = nrp + nup;
    for (int pi = wave; pi < ntot; pi += nwave) {
        if (pi < nrp) {
            const int rule = pi * 2 + half;
            const int h1 = p1[rule * 3 + 0], r1 = p1[rule * 3 + 1], t1 = p1[rule * 3 + 2];
            float c = sigmoidf_(triple_score_fp8(ent8, rel8, h1, r1, t1, l)) * conf[rule];
            if (tnum[rule] == 3) {
                const int h2 = p2[rule * 3 + 0], r2 = p2[rule * 3 + 1], t2 = p2[rule * 3 + 2];
                c *= sigmoidf_(triple_score_fp8(ent8, rel8, h2, r2, t2, l));
            }
            if (l == 0) atomicAdd(&pi_grad[uids[rule]], c);
        } else {
            const int i = (pi - nrp) * 2 + half;
            const int h = ut[i * 3 + 0], r = ut[i * 3 + 1], t = ut[i * 3 + 2];
            const float su = triple_score_fp8(ent8, rel8, h, r, t, l);
            if (l == 0) su_out[i] = su;
        }
    }
}

// ---- Kernel 3: unlabel loss + pos/neg softplus sums. Per-block partials. ----
__global__ void loss_kernel(const float* __restrict__ su,
                            const float* __restrict__ pi_grad,
                            const float* __restrict__ pos,
                            const float* __restrict__ neg,
                            float* __restrict__ lossp) {
    const int tid = blockIdx.x * blockDim.x + threadIdx.x;
    const int stride = gridDim.x * blockDim.x;
    float ul = 0.0f, ps = 0.0f, ns = 0.0f;
    for (int i = tid; i < N_UNLABEL; i += stride) {
        const float s   = su[i];
        const float p   = sigmoidf_(s);
        const float tgt = fminf(fmaxf(p + pi_grad[i], 0.0f), 1.0f);
        ul += tgt * softplusf_(-s) + (1.0f - tgt) * softplusf_(s);
    }
    const f32x4* posv = reinterpret_cast<const f32x4*>(pos);
    for (int i = tid; i < POS_LEN / 4; i += stride) {
        f32x4 v = __builtin_nontemporal_load(posv + i);
        ps += softplusf_(-v[0]) + softplusf_(-v[1]) + softplusf_(-v[2]) + softplusf_(-v[3]);
    }
    const f32x4* negv = reinterpret_cast<const f32x4*>(neg);
    for (int i = tid; i < (POS_LEN * NUM_NEG) / 4; i += stride) {
        f32x4 v = __builtin_nontemporal_load(negv + i);
        ns += softplusf_(v[0]) + softplusf_(v[1]) + softplusf_(v[2]) + softplusf_(v[3]);
    }
    ul = wave_sum64(ul); ps = wave_sum64(ps); ns = wave_sum64(ns);
    __shared__ float lu[8], lp[8], ln[8];
    const int lane = threadIdx.x & 63, wid = threadIdx.x >> 6;
    if (lane == 0) { lu[wid] = ul; lp[wid] = ps; ln[wid] = ns; }
    __syncthreads();
    if (threadIdx.x == 0) {
        float bu = 0.0f, bp = 0.0f, bn = 0.0f;
        for (int w = 0; w < (int)(blockDim.x >> 6); ++w) { bu += lu[w]; bp += lp[w]; bn += ln[w]; }
        lossp[blockIdx.x]                   = bu;
        lossp[LOSS_BLOCKS + blockIdx.x]     = bp;
        lossp[2 * LOSS_BLOCKS + blockIdx.x] = bn;
    }
}

// ---- Kernel 4: single-wave finalize in f64. ----
__global__ void finalize_kernel(const float* __restrict__ auxp,
                                const float* __restrict__ lossp,
                                float* __restrict__ out) {
    const int lane = threadIdx.x;  // 64 threads
    double sq = 0.0, ul = 0.0, ps = 0.0, ns = 0.0;
    for (int i = lane; i < AUX_BLOCKS; i += 64) sq += (double)auxp[i];
    for (int i = lane; i < LOSS_BLOCKS; i += 64) {
        ul += (double)lossp[i];
        ps += (double)lossp[LOSS_BLOCKS + i];
        ns += (double)lossp[2 * LOSS_BLOCKS + i];
    }
    sq = wave_sum64d(sq); ul = wave_sum64d(ul);
    ps = wave_sum64d(ps); ns = wave_sum64d(ns);
    if (lane == 0) {
        double v = ps / (double)POS_LEN
                 + ns / ((double)POS_LEN * (double)NUM_NEG)
                 + ul / (double)N_UNLABEL
                 + WEIGHT_DECAY * sq;
        out[0] = (float)v;
    }
}

extern "C" void kernel_launch(void* const* d_in, const int* in_sizes, int n_in,
                              void* d_out, int out_size, void* d_ws, size_t ws_size,
                              hipStream_t stream) {
    const float* pos  = (const float*)d_in[0];
    const float* neg  = (const float*)d_in[1];
    const float* conf = (const float*)d_in[2];
    const float* ent  = (const float*)d_in[3];
    const float* rel  = (const float*)d_in[4];
    const int*   p1   = (const int*)d_in[5];
    const int*   p2   = (const int*)d_in[6];
    const int*   tnum = (const int*)d_in[7];
    const int*   uids = (const int*)d_in[8];
    const int*   ut   = (const int*)d_in[9];

    // ws layout (all regions written unconditionally every call)
    const size_t off_pi    = 0;                                      // 512 KB
    const size_t off_su    = off_pi + (size_t)N_UNLABEL * 4;         // 512 KB
    const size_t off_auxp  = off_su + (size_t)N_UNLABEL * 4;         // 8 KB
    const size_t off_lossp = off_auxp + (size_t)AUX_BLOCKS * 4;      // 12 KB
    const size_t off_tab   = (off_lossp + (size_t)3 * LOSS_BLOCKS * 4 + 511) & ~(size_t)511;
    const size_t f16_need  = off_tab + (size_t)(NUM_ENT + NUM_REL) * EMB_DIM * 2;

    float* pi_grad = (float*)((char*)d_ws + off_pi);
    float* su      = (float*)((char*)d_ws + off_su);
    float* auxp    = (float*)((char*)d_ws + off_auxp);
    float* lossp   = (float*)((char*)d_ws + off_lossp);

    if (ws_size >= f16_need) {
        h8* ent16 = (h8*)((char*)d_ws + off_tab);
        h8* rel16 = (h8*)((char*)d_ws + off_tab + (size_t)NUM_ENT * EMB_DIM * 2);
        aux_f16_kernel<<<AUX_BLOCKS, 256, 0, stream>>>(ent, rel, ent16, rel16, pi_grad, auxp);
        gather_f16_kernel<<<GATHER_BLOCKS, 256, 0, stream>>>(conf, ent16, rel16, p1, p2,
                                                             tnum, uids, ut, pi_grad, su);
    } else {
        u32x2* ent8 = (u32x2*)((char*)d_ws + off_tab);
        u32x2* rel8 = (u32x2*)((char*)d_ws + off_tab + (size_t)NUM_ENT * EMB_DIM);
        aux_fp8_kernel<<<AUX_BLOCKS, 256, 0, stream>>>(ent, rel, ent8, rel8, pi_grad, auxp);
        gather_fp8_kernel<<<GATHER_BLOCKS, 256, 0, stream>>>(conf, ent8, rel8, p1, p2,
                                                             tnum, uids, ut, pi_grad, su);
    }
    loss_kernel<<<LOSS_BLOCKS, 256, 0, stream>>>(su, pi_grad, pos, neg, lossp);
    finalize_kernel<<<1, 64, 0, stream>>>(auxp, lossp, (float*)d_out);
}

// Round 7
// 101.347 us; speedup vs baseline: 1.3090x; 1.3090x over previous
//
#include <hip/hip_runtime.h>
#include <cstddef>
#include <cstdint>

#define POS_LEN    32768
#define NUM_NEG    64
#define N_RULES    262144
#define N_UNLABEL  131072
#define NUM_ENT    100000
#define NUM_REL    500
#define EMB_DIM    256
#define WEIGHT_DECAY 1e-5

#define AUX_BLOCKS    2048
#define GATHER_BLOCKS 2048
#define LOSS_BLOCKS   1024

typedef __attribute__((ext_vector_type(4))) float        f32x4;
typedef __attribute__((ext_vector_type(2))) unsigned int u32x2;
typedef __attribute__((ext_vector_type(4))) unsigned int u32x4;

__device__ __forceinline__ float softplusf_(float x) {
    return fmaxf(x, 0.0f) + log1pf(expf(-fabsf(x)));
}
__device__ __forceinline__ float sigmoidf_(float x) {
    return 1.0f / (1.0f + expf(-x));
}
__device__ __forceinline__ float quarter_sum16(float v) {   // reduce within 16-lane group
#pragma unroll
    for (int m = 1; m <= 8; m <<= 1) v += __shfl_xor(v, m, 64);
    return v;
}
__device__ __forceinline__ float wave_sum64(float v) {
#pragma unroll
    for (int m = 32; m >= 1; m >>= 1) v += __shfl_xor(v, m, 64);
    return v;
}
__device__ __forceinline__ double wave_sum64d(double v) {
#pragma unroll
    for (int m = 32; m >= 1; m >>= 1) v += __shfl_xor(v, m, 64);
    return v;
}

// ---- fp8 (OCP e4m3) pack/unpack via gfx950 HW converts (proven in R4) ----
__device__ __forceinline__ u32x2 f32x8_to_fp8(const f32x4 a, const f32x4 b) {
    int lo = 0, hi = 0;
    lo = __builtin_amdgcn_cvt_pk_fp8_f32(a[0], a[1], lo, false);
    lo = __builtin_amdgcn_cvt_pk_fp8_f32(a[2], a[3], lo, true);
    hi = __builtin_amdgcn_cvt_pk_fp8_f32(b[0], b[1], hi, false);
    hi = __builtin_amdgcn_cvt_pk_fp8_f32(b[2], b[3], hi, true);
    u32x2 r; r[0] = (unsigned)lo; r[1] = (unsigned)hi; return r;
}
__device__ __forceinline__ void fp8x4_to_f32(unsigned int w, float* o) {
    auto x = __builtin_amdgcn_cvt_pk_f32_fp8((int)w, false);
    auto y = __builtin_amdgcn_cvt_pk_f32_fp8((int)w, true);
    o[0] = x[0]; o[1] = x[1]; o[2] = y[0]; o[3] = y[1];
}

// Quarter-wave tri-product over 16 fp8 elems per lane (16 lanes x 16 = 256 dims).
// Word-at-a-time convert+fma keeps live registers low.
__device__ __forceinline__ float dot3_q(const u32x4 hv, const u32x4 rv, const u32x4 tv) {
    float s = 0.0f;
#pragma unroll
    for (int w = 0; w < 4; ++w) {
        float hf[4], rf[4], tf[4];
        fp8x4_to_f32(hv[w], hf);
        fp8x4_to_f32(rv[w], rf);
        fp8x4_to_f32(tv[w], tf);
        s = fmaf(hf[0] * rf[0], tf[0], s);
        s = fmaf(hf[1] * rf[1], tf[1], s);
        s = fmaf(hf[2] * rf[2], tf[2], s);
        s = fmaf(hf[3] * rf[3], tf[3], s);
    }
    return quarter_sum16(s);
}

// ---- Kernel 1: quantize ent/rel -> fp8, sum-of-squares (f32 exact),
//      zero pi_grad. Streaming reads non-temporal. Per-block partials. ----
__global__ void aux_fp8_kernel(const float* __restrict__ ent,
                               const float* __restrict__ rel,
                               u32x2* __restrict__ ent8,
                               u32x2* __restrict__ rel8,
                               float* __restrict__ pi_grad,
                               float* __restrict__ auxp) {
    const int tid = blockIdx.x * blockDim.x + threadIdx.x;
    const int stride = gridDim.x * blockDim.x;
    for (int i = tid; i < N_UNLABEL; i += stride) pi_grad[i] = 0.0f;
    float sq = 0.0f;
    const f32x4* entv = reinterpret_cast<const f32x4*>(ent);
    for (int i = tid; i < (NUM_ENT * EMB_DIM) / 8; i += stride) {
        f32x4 a = __builtin_nontemporal_load(entv + (size_t)i * 2);
        f32x4 b = __builtin_nontemporal_load(entv + (size_t)i * 2 + 1);
        sq += a[0]*a[0] + a[1]*a[1] + a[2]*a[2] + a[3]*a[3]
            + b[0]*b[0] + b[1]*b[1] + b[2]*b[2] + b[3]*b[3];
        ent8[i] = f32x8_to_fp8(a, b);
    }
    const f32x4* relv = reinterpret_cast<const f32x4*>(rel);
    for (int i = tid; i < (NUM_REL * EMB_DIM) / 8; i += stride) {
        f32x4 a = __builtin_nontemporal_load(relv + (size_t)i * 2);
        f32x4 b = __builtin_nontemporal_load(relv + (size_t)i * 2 + 1);
        sq += a[0]*a[0] + a[1]*a[1] + a[2]*a[2] + a[3]*a[3]
            + b[0]*b[0] + b[1]*b[1] + b[2]*b[2] + b[3]*b[3];
        rel8[i] = f32x8_to_fp8(a, b);
    }
    sq = wave_sum64(sq);
    __shared__ float ls[8];
    const int lane = threadIdx.x & 63, wid = threadIdx.x >> 6;
    if (lane == 0) ls[wid] = sq;
    __syncthreads();
    if (threadIdx.x == 0) {
        float bs = 0.0f;
        for (int w = 0; w < (int)(blockDim.x >> 6); ++w) bs += ls[w];
        auxp[blockIdx.x] = bs;
    }
}

// ---- Kernel 2: fused fp8 gathers, quarter-wave (4 triples/wave).
// All row loads (p1 + predicated p2) are issued before any convert math. ----
__global__ void gather_kernel(const float* __restrict__ conf,
                              const u32x4* __restrict__ ent8,
                              const u32x4* __restrict__ rel8,
                              const int* __restrict__ p1,
                              const int* __restrict__ p2,
                              const int* __restrict__ tnum,
                              const int* __restrict__ uids,
                              const int* __restrict__ ut,
                              float* __restrict__ pi_grad,
                              float* __restrict__ su_out) {
    const int lane = threadIdx.x & 63;
    const int l    = lane & 15;
    const int q    = lane >> 4;   // quarter 0..3
    const int wave  = blockIdx.x * (blockDim.x >> 6) + (threadIdx.x >> 6);
    const int nwave = gridDim.x * (blockDim.x >> 6);
    const int nr4 = N_RULES / 4, nu4 = N_UNLABEL / 4, ntot = nr4 + nu4;

    for (int pi = wave; pi < ntot; pi += nwave) {
        if (pi < nr4) {
            const int rule = pi * 4 + q;
            const int b = rule * 3;
            // index/scalar loads first
            const int h1 = p1[b], r1 = p1[b + 1], t1 = p1[b + 2];
            const int tn = tnum[rule];
            const float cf = conf[rule];
            const int uid = uids[rule];
            const bool has2 = (tn == 3);
            // issue ALL row loads up front
            const u32x4 H1 = ent8[(size_t)h1 * 16 + l];
            const u32x4 R1 = rel8[(size_t)r1 * 16 + l];
            const u32x4 T1 = ent8[(size_t)t1 * 16 + l];
            u32x4 H2 = {0, 0, 0, 0}, R2 = {0, 0, 0, 0}, T2 = {0, 0, 0, 0};
            if (has2) {
                const int h2 = p2[b], r2 = p2[b + 1], t2 = p2[b + 2];
                H2 = ent8[(size_t)h2 * 16 + l];
                R2 = rel8[(size_t)r2 * 16 + l];
                T2 = ent8[(size_t)t2 * 16 + l];
            }
            // now the convert/fma chains
            float c = sigmoidf_(dot3_q(H1, R1, T1)) * cf;
            if (has2) c *= sigmoidf_(dot3_q(H2, R2, T2));
            if (l == 0) atomicAdd(&pi_grad[uid], c);
        } else {
            const int i = (pi - nr4) * 4 + q;
            const int b = i * 3;
            const int h = ut[b], r = ut[b + 1], t = ut[b + 2];
            const u32x4 H = ent8[(size_t)h * 16 + l];
            const u32x4 R = rel8[(size_t)r * 16 + l];
            const u32x4 T = ent8[(size_t)t * 16 + l];
            const float su = dot3_q(H, R, T);
            if (l == 0) su_out[i] = su;
        }
    }
}

// ---- Kernel 3: unlabel loss + pos/neg softplus sums. Per-block partials. ----
__global__ void loss_kernel(const float* __restrict__ su,
                            const float* __restrict__ pi_grad,
                            const float* __restrict__ pos,
                            const float* __restrict__ neg,
                            float* __restrict__ lossp) {
    const int tid = blockIdx.x * blockDim.x + threadIdx.x;
    const int stride = gridDim.x * blockDim.x;
    float ul = 0.0f, ps = 0.0f, ns = 0.0f;
    for (int i = tid; i < N_UNLABEL; i += stride) {
        const float s   = su[i];
        const float p   = sigmoidf_(s);
        const float tgt = fminf(fmaxf(p + pi_grad[i], 0.0f), 1.0f);
        ul += tgt * softplusf_(-s) + (1.0f - tgt) * softplusf_(s);
    }
    const f32x4* posv = reinterpret_cast<const f32x4*>(pos);
    for (int i = tid; i < POS_LEN / 4; i += stride) {
        f32x4 v = __builtin_nontemporal_load(posv + i);
        ps += softplusf_(-v[0]) + softplusf_(-v[1]) + softplusf_(-v[2]) + softplusf_(-v[3]);
    }
    const f32x4* negv = reinterpret_cast<const f32x4*>(neg);
    for (int i = tid; i < (POS_LEN * NUM_NEG) / 4; i += stride) {
        f32x4 v = __builtin_nontemporal_load(negv + i);
        ns += softplusf_(v[0]) + softplusf_(v[1]) + softplusf_(v[2]) + softplusf_(v[3]);
    }
    ul = wave_sum64(ul); ps = wave_sum64(ps); ns = wave_sum64(ns);
    __shared__ float lu[8], lp[8], ln[8];
    const int lane = threadIdx.x & 63, wid = threadIdx.x >> 6;
    if (lane == 0) { lu[wid] = ul; lp[wid] = ps; ln[wid] = ns; }
    __syncthreads();
    if (threadIdx.x == 0) {
        float bu = 0.0f, bp = 0.0f, bn = 0.0f;
        for (int w = 0; w < (int)(blockDim.x >> 6); ++w) { bu += lu[w]; bp += lp[w]; bn += ln[w]; }
        lossp[blockIdx.x]                   = bu;
        lossp[LOSS_BLOCKS + blockIdx.x]     = bp;
        lossp[2 * LOSS_BLOCKS + blockIdx.x] = bn;
    }
}

// ---- Kernel 4: single-wave finalize in f64. ----
__global__ void finalize_kernel(const float* __restrict__ auxp,
                                const float* __restrict__ lossp,
                                float* __restrict__ out) {
    const int lane = threadIdx.x;  // 64 threads
    double sq = 0.0, ul = 0.0, ps = 0.0, ns = 0.0;
    for (int i = lane; i < AUX_BLOCKS; i += 64) sq += (double)auxp[i];
    for (int i = lane; i < LOSS_BLOCKS; i += 64) {
        ul += (double)lossp[i];
        ps += (double)lossp[LOSS_BLOCKS + i];
        ns += (double)lossp[2 * LOSS_BLOCKS + i];
    }
    sq = wave_sum64d(sq); ul = wave_sum64d(ul);
    ps = wave_sum64d(ps); ns = wave_sum64d(ns);
    if (lane == 0) {
        double v = ps / (double)POS_LEN
                 + ns / ((double)POS_LEN * (double)NUM_NEG)
                 + ul / (double)N_UNLABEL
                 + WEIGHT_DECAY * sq;
        out[0] = (float)v;
    }
}

extern "C" void kernel_launch(void* const* d_in, const int* in_sizes, int n_in,
                              void* d_out, int out_size, void* d_ws, size_t ws_size,
                              hipStream_t stream) {
    const float* pos  = (const float*)d_in[0];
    const float* neg  = (const float*)d_in[1];
    const float* conf = (const float*)d_in[2];
    const float* ent  = (const float*)d_in[3];
    const float* rel  = (const float*)d_in[4];
    const int*   p1   = (const int*)d_in[5];
    const int*   p2   = (const int*)d_in[6];
    const int*   tnum = (const int*)d_in[7];
    const int*   uids = (const int*)d_in[8];
    const int*   ut   = (const int*)d_in[9];

    // ws layout (all regions written unconditionally every call)
    const size_t off_pi    = 0;                                      // 512 KB
    const size_t off_su    = off_pi + (size_t)N_UNLABEL * 4;         // 512 KB
    const size_t off_auxp  = off_su + (size_t)N_UNLABEL * 4;         // 8 KB
    const size_t off_lossp = off_auxp + (size_t)AUX_BLOCKS * 4;      // 12 KB
    const size_t off_tab   = (off_lossp + (size_t)3 * LOSS_BLOCKS * 4 + 511) & ~(size_t)511;
    const size_t off_rel8  = off_tab + (size_t)NUM_ENT * EMB_DIM;    // fp8: 1 B/elem

    float* pi_grad = (float*)((char*)d_ws + off_pi);
    float* su      = (float*)((char*)d_ws + off_su);
    float* auxp    = (float*)((char*)d_ws + off_auxp);
    float* lossp   = (float*)((char*)d_ws + off_lossp);
    u32x2* ent8w   = (u32x2*)((char*)d_ws + off_tab);
    u32x2* rel8w   = (u32x2*)((char*)d_ws + off_rel8);

    aux_fp8_kernel<<<AUX_BLOCKS, 256, 0, stream>>>(ent, rel, ent8w, rel8w, pi_grad, auxp);
    gather_kernel<<<GATHER_BLOCKS, 256, 0, stream>>>(conf,
                                                     (const u32x4*)((char*)d_ws + off_tab),
                                                     (const u32x4*)((char*)d_ws + off_rel8),
                                                     p1, p2, tnum, uids, ut, pi_grad, su);
    loss_kernel<<<LOSS_BLOCKS, 256, 0, stream>>>(su, pi_grad, pos, neg, lossp);
    finalize_kernel<<<1, 64, 0, stream>>>(auxp, lossp, (float*)d_out);
}